// Round 3
// baseline (173.074 us; speedup 1.0000x reference)
//
#include <hip/hip_runtime.h>

// B=4, S=4096, D=64, fp32. Softmax over QUERY axis (per key-column norm):
//   out[b,q,:] = sum_k exp(s[q,k]) * (1/sum_q' exp(s[q',k])) * V[k,:],  s = Q.K^T/8
// v3: barrier-free register-direct design.
//   prep_split: K,Q -> hi/lo bf16 interleaved images (Q pre-scaled by 0.125*log2e)
//   stats3: column sums, K-frags register-resident, Q frags streamed from image (no barriers)
//   finalize8 -> rcpl; prepV3: VT image (rcpl folded), ALIASES Q image (stats done)
//   apply3: 512 blocks (2/CU), 4 waves = 4 k-quarters, K/V frags direct from L2-resident
//           images, P via wave-private LDS (lgkm only), ONE barrier (final merge).
// Numerics identical per-term to round-2 (hi/lo split, 3-MFMA products).

#define B_N 4
#define S_N 4096
#define D_N 64
#define BS_N (B_N * S_N)
#define NCHUNK 128            // 32-row chunks per batch
#define IMG_CH 8192           // bytes per chunk in every image
#define QSC (0.125f * 1.44269504088896f)

typedef __attribute__((ext_vector_type(4))) float f32x4;
typedef __attribute__((ext_vector_type(8))) short short8;
typedef unsigned long long u64;
typedef unsigned char uchar;

#define MFMA16(A, Bf, C) __builtin_amdgcn_mfma_f32_16x16x32_bf16((A), (Bf), (C), 0, 0, 0)

// Truncation hi/lo split: x == hi + lo + O(2^-16 x); residual exact in fp32.
__device__ __forceinline__ void split1(float x, unsigned short& h, unsigned short& l) {
  union { float f; unsigned u; } t; t.f = x;
  h = (unsigned short)(t.u >> 16);
  union { unsigned u; float f; } hv; hv.u = ((unsigned)h) << 16;
  union { float f; unsigned u; } r; r.f = x - hv.f;
  l = (unsigned short)(r.u >> 16);
}

__device__ __forceinline__ void split4(const f32x4 v, u64& hb, u64& lb) {
  hb = 0ull; lb = 0ull;
#pragma unroll
  for (int j = 0; j < 4; ++j) {
    unsigned short h, l; split1(v[j], h, l);
    hb |= ((u64)h) << (16 * j);
    lb |= ((u64)l) << (16 * j);
  }
}

__device__ __forceinline__ void splitFrag8(const f32x4 a, const f32x4 b, short8& hi, short8& lo) {
#pragma unroll
  for (int j = 0; j < 4; ++j) { unsigned short h, l; split1(a[j], h, l); hi[j] = (short)h; lo[j] = (short)l; }
#pragma unroll
  for (int j = 0; j < 4; ++j) { unsigned short h, l; split1(b[j], h, l); hi[4 + j] = (short)h; lo[4 + j] = (short)l; }
}

// ---------------------------------------------------------------------------
// prep_split: fp32 [B*S][64] -> chunk images: row r (32/chunk) = [hi 128B][lo 128B].
// grid 512 = b*128+c, block 256 (each thread: 8 d of one row).
// ---------------------------------------------------------------------------
__global__ __launch_bounds__(256) void sdpa_prep_split(const float* __restrict__ src,
                                                       uchar* __restrict__ img, float scale) {
  const int c = blockIdx.x & 127;
  const int b = blockIdx.x >> 7;
  const int t = threadIdx.x;
  const int r = t >> 3;
  const int d0 = (t & 7) * 8;
  const float* s = src + ((size_t)(b * S_N + c * 32 + r)) * D_N + d0;
  f32x4 x0 = *(const f32x4*)(s);
  f32x4 x1 = *(const f32x4*)(s + 4);
  x0 *= scale; x1 *= scale;
  short8 h8, l8;
  splitFrag8(x0, x1, h8, l8);
  uchar* dst = img + ((size_t)(b * NCHUNK + c)) * IMG_CH + r * 256 + d0 * 2;
  *(short8*)(dst) = h8;
  *(short8*)(dst + 128) = l8;
}

// ---------------------------------------------------------------------------
// stats3: lPart[qs][b][k] = sum over q-slice qs (512 q) of exp2(min(s,86)).
// grid 512 (2 blocks/CU), block 256; wave w = q-slice (qs = (r>>5)*4 + w).
// Wave holds 64 k of K resident in regs; streams 16 Q-chunks. NO barriers.
// ---------------------------------------------------------------------------
__global__ __launch_bounds__(256, 2) void sdpa_stats3(const uchar* __restrict__ Kimg,
                                                      const uchar* __restrict__ Qimg,
                                                      float* __restrict__ lPart) {
  const int tid = threadIdx.x, lane = tid & 63, w = tid >> 6;
  const int l15 = lane & 15, g4 = lane >> 4;
  const int xcd = blockIdx.x & 7;
  const int b = xcd >> 1;
  const int r = blockIdx.x >> 3;                  // [0,64)
  const int kt = ((r & 31) << 1) | (xcd & 1);     // [0,64) k-tile of 64
  const int qs = ((r >> 5) << 2) | w;             // [0,8) q-slice of 512

  // K resident: kg 0..3 -> rows kt*64+kg*16+l15 (chunk kt*2+(kg>>1))
  short8 kh[4][2], kl[4][2];
#pragma unroll
  for (int kg = 0; kg < 4; ++kg) {
    const uchar* kb = Kimg + ((size_t)(b * NCHUNK + kt * 2 + (kg >> 1))) * IMG_CH
                    + ((kg & 1) * 16 + l15) * 256 + (g4 << 4);
    kh[kg][0] = *(const short8*)(kb);
    kh[kg][1] = *(const short8*)(kb + 64);
    kl[kg][0] = *(const short8*)(kb + 128);
    kl[kg][1] = *(const short8*)(kb + 192);
  }

  float lacc[4][4];
#pragma unroll
  for (int kg = 0; kg < 4; ++kg)
#pragma unroll
    for (int rr = 0; rr < 4; ++rr) lacc[kg][rr] = 0.f;

  const uchar* Qc = Qimg + ((size_t)(b * NCHUNK + qs * 16)) * IMG_CH;
  for (int it = 0; it < 16; ++it) {
#pragma unroll
    for (int qt = 0; qt < 2; ++qt) {
      const uchar* qb = Qc + (qt * 16 + l15) * 256 + (g4 << 4);
      short8 bh0 = *(const short8*)(qb);
      short8 bh1 = *(const short8*)(qb + 64);
      short8 bl0 = *(const short8*)(qb + 128);
      short8 bl1 = *(const short8*)(qb + 192);
#pragma unroll
      for (int kg = 0; kg < 4; ++kg) {
        f32x4 acc = {0.f, 0.f, 0.f, 0.f};
        acc = MFMA16(kl[kg][0], bh0, acc);
        acc = MFMA16(kh[kg][0], bl0, acc);
        acc = MFMA16(kh[kg][0], bh0, acc);
        acc = MFMA16(kl[kg][1], bh1, acc);
        acc = MFMA16(kh[kg][1], bl1, acc);
        acc = MFMA16(kh[kg][1], bh1, acc);
#pragma unroll
        for (int rr = 0; rr < 4; ++rr)
          lacc[kg][rr] += exp2f(fminf(acc[rr], 86.f));
      }
    }
    Qc += IMG_CH;
  }

#pragma unroll
  for (int off = 1; off < 16; off <<= 1)
#pragma unroll
    for (int kg = 0; kg < 4; ++kg)
#pragma unroll
      for (int rr = 0; rr < 4; ++rr)
        lacc[kg][rr] += __shfl_xor(lacc[kg][rr], off);

  if (l15 == 0) {
#pragma unroll
    for (int kg = 0; kg < 4; ++kg)
#pragma unroll
      for (int rr = 0; rr < 4; ++rr)
        lPart[(size_t)qs * BS_N + b * S_N + kt * 64 + kg * 16 + (g4 << 2) + rr] = lacc[kg][rr];
  }
}

__global__ void sdpa_finalize8(const float* __restrict__ lPart, float* __restrict__ rcpl) {
  int i = blockIdx.x * 256 + threadIdx.x;
  if (i < BS_N) {
    float s = 0.f;
#pragma unroll
    for (int j = 0; j < 8; ++j) s += lPart[(size_t)j * BS_N + i];
    rcpl[i] = 1.0f / s;
  }
}

// ---------------------------------------------------------------------------
// prepV3: VT chunk images: row d (64/chunk) = [hi 64B: 32 k][lo 64B], value
// bf16 split of V[k][d] * rcpl[k]. grid 512, block 256, LDS transpose.
// ---------------------------------------------------------------------------
__global__ __launch_bounds__(256) void sdpa_prepV3(const float* __restrict__ V,
                                                   const float* __restrict__ rcpl,
                                                   uchar* __restrict__ VT) {
  __shared__ float Vs[32][65];
  __shared__ float rls[32];
  const int c = blockIdx.x & 127;
  const int b = blockIdx.x >> 7;
  const int t = threadIdx.x;
  {
    const int k = t >> 3;
    const int d0 = (t & 7) * 8;
    const float* src = V + ((size_t)(b * S_N + c * 32 + k)) * D_N + d0;
    f32x4 x0 = *(const f32x4*)(src);
    f32x4 x1 = *(const f32x4*)(src + 4);
#pragma unroll
    for (int j = 0; j < 4; ++j) { Vs[k][d0 + j] = x0[j]; Vs[k][d0 + 4 + j] = x1[j]; }
    if (t < 32) rls[t] = rcpl[b * S_N + c * 32 + t];
  }
  __syncthreads();
  const int d = t >> 2;
  const int kg = t & 3;
  short8 h8, l8;
#pragma unroll
  for (int j = 0; j < 8; ++j) {
    int k = kg * 8 + j;
    float v = Vs[k][d] * rls[k];
    unsigned short h, l; split1(v, h, l);
    h8[j] = (short)h; l8[j] = (short)l;
  }
  uchar* dst = VT + ((size_t)(b * NCHUNK + c)) * IMG_CH + d * 128 + kg * 16;
  *(short8*)(dst) = h8;
  *(short8*)(dst + 64) = l8;
}

// ---------------------------------------------------------------------------
// apply3: grid 512 = b(4, XCD-paired) x qt(128 tiles of 32 q); block 256.
// Wave w = k-quarter (1024 k, 32 chunk-iters). All operands direct from L2.
// P through wave-private double-buffered LDS; one barrier pair at merge.
// ---------------------------------------------------------------------------
__global__ __launch_bounds__(256, 2) void sdpa_apply3(const float* __restrict__ Q,
                                                      const uchar* __restrict__ Kimg,
                                                      const uchar* __restrict__ VTimg,
                                                      float* __restrict__ Out) {
  // P: 4 waves x 2 bufs x (PH 2560 | PL 2560) = 40960; Comb merge (after barrier):
  // 4 waves x 32 q x 68 f32 = 34816. Union = 40960.
  __shared__ __attribute__((aligned(16))) uchar sm[40960];

  const int tid = threadIdx.x, lane = tid & 63, w = tid >> 6;
  const int l15 = lane & 15, g4 = lane >> 4;
  const int xcd = blockIdx.x & 7;
  const int b = xcd >> 1;
  const int qt = ((blockIdx.x >> 3) << 1) | (xcd & 1);  // [0,128)

  // Q B-frags: raw fp32, scaled by QSC, hi/lo split (once per wave)
  short8 qh[2][2], ql[2][2];
#pragma unroll
  for (int qg = 0; qg < 2; ++qg) {
    const int qRow = qt * 32 + qg * 16 + l15;
    const float* Qp = Q + ((size_t)(b * S_N + qRow)) * D_N;
    f32x4 x0 = *(const f32x4*)(Qp + g4 * 8);
    f32x4 x1 = *(const f32x4*)(Qp + g4 * 8 + 4);
    f32x4 y0 = *(const f32x4*)(Qp + 32 + g4 * 8);
    f32x4 y1 = *(const f32x4*)(Qp + 36 + g4 * 8);
    x0 *= QSC; x1 *= QSC; y0 *= QSC; y1 *= QSC;
    splitFrag8(x0, x1, qh[qg][0], ql[qg][0]);
    splitFrag8(y0, y1, qh[qg][1], ql[qg][1]);
  }

  f32x4 accO[2][4];
#pragma unroll
  for (int qg = 0; qg < 2; ++qg)
#pragma unroll
    for (int dt = 0; dt < 4; ++dt) accO[qg][dt] = (f32x4){0.f, 0.f, 0.f, 0.f};

  const uchar* Kc = Kimg + ((size_t)(b * NCHUNK + w * 32)) * IMG_CH;
  const uchar* Vc = VTimg + ((size_t)(b * NCHUNK + w * 32)) * IMG_CH;

#pragma unroll 2
  for (int it = 0; it < 32; ++it) {
    uchar* PH = sm + w * 5120 + (it & 1) * 20480;  // wave-private, double-buffered
    uchar* PL = PH + 2560;

    // QK^T swapped (A=K, B=Q): D[k][q]; k = kt*16+g4*4+r, q = l15
#pragma unroll
    for (int kt = 0; kt < 2; ++kt) {
      const uchar* kb = Kc + (kt * 16 + l15) * 256 + (g4 << 4);
      short8 ah0 = *(const short8*)(kb);
      short8 ah1 = *(const short8*)(kb + 64);
      short8 al0 = *(const short8*)(kb + 128);
      short8 al1 = *(const short8*)(kb + 192);
#pragma unroll
      for (int qg = 0; qg < 2; ++qg) {
        f32x4 acc = {0.f, 0.f, 0.f, 0.f};
        acc = MFMA16(al0, qh[qg][0], acc);
        acc = MFMA16(ah0, ql[qg][0], acc);
        acc = MFMA16(ah0, qh[qg][0], acc);
        acc = MFMA16(al1, qh[qg][1], acc);
        acc = MFMA16(ah1, ql[qg][1], acc);
        acc = MFMA16(ah1, qh[qg][1], acc);
        u64 ph = 0ull, pl = 0ull;
#pragma unroll
        for (int r = 0; r < 4; ++r) {
          float p = exp2f(fminf(acc[r], 86.f));
          unsigned short h, l; split1(p, h, l);
          ph |= ((u64)h) << (16 * r);
          pl |= ((u64)l) << (16 * r);
        }
        const int poff = (qg * 16 + l15) * 80 + kt * 32 + (g4 << 3);
        *(u64*)(PH + poff) = ph;
        *(u64*)(PL + poff) = pl;
      }
    }

    // P A-frags (same-wave LDS round-trip, lgkm-ordered by compiler)
    short8 pah[2], pal[2];
#pragma unroll
    for (int qg = 0; qg < 2; ++qg) {
      const int poff = (qg * 16 + l15) * 80 + (g4 << 4);
      pah[qg] = *(const short8*)(PH + poff);
      pal[qg] = *(const short8*)(PL + poff);
    }

    // PV: B-frags direct from VT image
#pragma unroll
    for (int dt = 0; dt < 4; ++dt) {
      const uchar* vb = Vc + (dt * 16 + l15) * 128 + (g4 << 4);
      short8 vh = *(const short8*)(vb);
      short8 vl = *(const short8*)(vb + 64);
#pragma unroll
      for (int qg = 0; qg < 2; ++qg) {
        accO[qg][dt] = MFMA16(pal[qg], vh, accO[qg][dt]);
        accO[qg][dt] = MFMA16(pah[qg], vl, accO[qg][dt]);
        accO[qg][dt] = MFMA16(pah[qg], vh, accO[qg][dt]);
      }
    }
    Kc += IMG_CH; Vc += IMG_CH;
  }

  // merge the 4 k-quarter partials (only barriers in the kernel)
  __syncthreads();
  float* CombW = (float*)sm + (size_t)w * 32 * 68;
#pragma unroll
  for (int qg = 0; qg < 2; ++qg)
#pragma unroll
    for (int dt = 0; dt < 4; ++dt)
#pragma unroll
      for (int r = 0; r < 4; ++r)
        CombW[(qg * 16 + (g4 << 2) + r) * 68 + dt * 16 + l15] = accO[qg][dt][r];
  __syncthreads();
  {
    const int row = tid >> 3;   // 0..31
    const int cb = tid & 7;     // 0..7
    const float* Cm = (const float*)sm;
    f32x4 s0 = {0.f, 0.f, 0.f, 0.f}, s1 = {0.f, 0.f, 0.f, 0.f};
#pragma unroll
    for (int w2 = 0; w2 < 4; ++w2) {
      const float* p = Cm + (size_t)w2 * 32 * 68 + row * 68 + cb * 8;
      s0 += *(const f32x4*)(p);
      s1 += *(const f32x4*)(p + 4);
    }
    float* Op = Out + ((size_t)(b * S_N + qt * 32 + row)) * D_N + cb * 8;
    *(f32x4*)(Op) = s0;
    *(f32x4*)(Op + 4) = s1;
  }
}

// ---------------------------------------------------------------------------
// Fallback path (ws too small): round-1 kernels, proven correct.
// ---------------------------------------------------------------------------
__global__ __launch_bounds__(256, 2) void sdpa_stats(const float* __restrict__ Q,
                                                     const float* __restrict__ K,
                                                     float* __restrict__ lPart) {
  __shared__ __attribute__((aligned(16))) unsigned short Qh[64][72];
  __shared__ __attribute__((aligned(16))) unsigned short Ql[64][72];
  const int tid = threadIdx.x;
  const int lane = tid & 63;
  const int w = tid >> 6;
  const int qs = blockIdx.x & 1;
  const int kb = (blockIdx.x >> 1) & 63;
  const int b = blockIdx.x >> 7;
  const int l15 = lane & 15;
  const int dbase = (lane >> 4) << 3;
  const int kA = kb * 64 + w * 16 + l15;
  const float* Kp = K + ((size_t)(b * S_N + kA)) * D_N;
  short8 ah0, al0, ah1, al1;
  {
    f32x4 x0 = *(const f32x4*)(Kp + dbase);
    f32x4 x1 = *(const f32x4*)(Kp + dbase + 4);
    f32x4 y0 = *(const f32x4*)(Kp + 32 + dbase);
    f32x4 y1 = *(const f32x4*)(Kp + 36 + dbase);
    splitFrag8(x0, x1, ah0, al0);
    splitFrag8(y0, y1, ah1, al1);
  }
  float lacc[4] = {0.f, 0.f, 0.f, 0.f};
  const float* Qb = Q + ((size_t)b) * S_N * D_N;
  for (int it = 0; it < 32; ++it) {
    const int q0 = qs * 2048 + it * 64;
    __syncthreads();
#pragma unroll
    for (int rep = 0; rep < 4; ++rep) {
      int idx = rep * 256 + tid;
      int q = idx >> 4;
      int dv = (idx & 15) << 2;
      f32x4 v = *(const f32x4*)(Qb + ((size_t)(q0 + q)) * D_N + dv);
      u64 hb, lb; split4(v, hb, lb);
      *(u64*)&Qh[q][dv] = hb;
      *(u64*)&Ql[q][dv] = lb;
    }
    __syncthreads();
#pragma unroll
    for (int sub = 0; sub < 4; ++sub) {
      const int qr = sub * 16 + l15;
      short8 bh0 = *(const short8*)&Qh[qr][dbase];
      short8 bl0 = *(const short8*)&Ql[qr][dbase];
      short8 bh1 = *(const short8*)&Qh[qr][32 + dbase];
      short8 bl1 = *(const short8*)&Ql[qr][32 + dbase];
      f32x4 acc = {0.f, 0.f, 0.f, 0.f};
      acc = MFMA16(al0, bh0, acc);
      acc = MFMA16(ah0, bl0, acc);
      acc = MFMA16(ah0, bh0, acc);
      acc = MFMA16(al1, bh1, acc);
      acc = MFMA16(ah1, bl1, acc);
      acc = MFMA16(ah1, bh1, acc);
#pragma unroll
      for (int r = 0; r < 4; ++r)
        lacc[r] += __expf(fminf(acc[r] * 0.125f, 60.f));
    }
  }
#pragma unroll
  for (int off = 1; off < 16; off <<= 1)
#pragma unroll
    for (int r = 0; r < 4; ++r)
      lacc[r] += __shfl_xor(lacc[r], off);
  if (l15 == 0) {
    const int kOut = kb * 64 + w * 16 + (lane >> 4) * 4;
#pragma unroll
    for (int r = 0; r < 4; ++r)
      lPart[qs * BS_N + b * S_N + kOut + r] = lacc[r];
  }
}

__global__ void sdpa_finalize(const float* __restrict__ lPart, float* __restrict__ rcpl) {
  int i = blockIdx.x * 256 + threadIdx.x;
  if (i < BS_N) rcpl[i] = 1.0f / (lPart[i] + lPart[BS_N + i]);
}

__global__ __launch_bounds__(256, 2) void sdpa_apply_v1(const float* __restrict__ Q,
                                                        const float* __restrict__ K,
                                                        const float* __restrict__ V,
                                                        const float* __restrict__ rcpl,
                                                        float* __restrict__ Out) {
  __shared__ __attribute__((aligned(16))) unsigned short Kh[2][32][72];
  __shared__ __attribute__((aligned(16))) unsigned short Kl[2][32][72];
  __shared__ __attribute__((aligned(16))) unsigned short Vth[2][64][40];
  __shared__ __attribute__((aligned(16))) unsigned short Vtl[2][64][40];
  __shared__ __attribute__((aligned(16))) unsigned short Ph[4][16][40];
  __shared__ __attribute__((aligned(16))) unsigned short Pl[4][16][40];
  __shared__ float Comb[2][16][66];
  const int tid = threadIdx.x;
  const int lane = tid & 63;
  const int w = tid >> 6;
  const int qsub = w & 1;
  const int par = w >> 1;
  const int qBlk = blockIdx.x & 127;
  const int b = blockIdx.x >> 7;
  const int l15 = lane & 15;
  const int dbase = (lane >> 4) << 3;
  const float* Qb = Q + ((size_t)b) * S_N * D_N;
  const float* Kb = K + ((size_t)b) * S_N * D_N;
  const float* Vb = V + ((size_t)b) * S_N * D_N;
  const float* rlb = rcpl + b * S_N;
  short8 qh0, ql0, qh1, ql1;
  {
    const int qRow = qBlk * 32 + qsub * 16 + l15;
    const float* Qp = Qb + ((size_t)qRow) * D_N;
    f32x4 x0 = *(const f32x4*)(Qp + dbase);
    f32x4 x1 = *(const f32x4*)(Qp + dbase + 4);
    f32x4 y0 = *(const f32x4*)(Qp + 32 + dbase);
    f32x4 y1 = *(const f32x4*)(Qp + 36 + dbase);
    splitFrag8(x0, x1, qh0, ql0);
    splitFrag8(y0, y1, qh1, ql1);
  }
  f32x4 accO[4];
#pragma unroll
  for (int i = 0; i < 4; ++i) accO[i] = (f32x4){0.f, 0.f, 0.f, 0.f};
  for (int it = 0; it < 64; ++it) {
    __syncthreads();
#pragma unroll
    for (int pb = 0; pb < 2; ++pb) {
      const int c = it * 2 + pb;
      const float* Kc = Kb + ((size_t)c) * 32 * D_N;
      const float* Vc = Vb + ((size_t)c) * 32 * D_N;
#pragma unroll
      for (int rep = 0; rep < 2; ++rep) {
        int idx = rep * 256 + tid;
        int kl = idx >> 4;
        int dv = (idx & 15) << 2;
        f32x4 kv = *(const f32x4*)(Kc + ((size_t)kl) * D_N + dv);
        u64 hb, lb; split4(kv, hb, lb);
        *(u64*)&Kh[pb][kl][dv] = hb;
        *(u64*)&Kl[pb][kl][dv] = lb;
        f32x4 vv = *(const f32x4*)(Vc + ((size_t)kl) * D_N + dv);
#pragma unroll
        for (int j = 0; j < 4; ++j) {
          unsigned short h, l; split1(vv[j], h, l);
          int d = dv + j;
          int col = (((kl >> 3) ^ ((d >> 3) & 3)) << 3) | (kl & 7);
          Vth[pb][d][col] = h;
          Vtl[pb][d][col] = l;
        }
      }
    }
    __syncthreads();
    const int c = it * 2 + par;
#pragma unroll
    for (int sub = 0; sub < 2; ++sub) {
      const int kr = sub * 16 + l15;
      short8 bh0 = *(const short8*)&Kh[par][kr][dbase];
      short8 bl0 = *(const short8*)&Kl[par][kr][dbase];
      short8 bh1 = *(const short8*)&Kh[par][kr][32 + dbase];
      short8 bl1 = *(const short8*)&Kl[par][kr][32 + dbase];
      f32x4 acc = {0.f, 0.f, 0.f, 0.f};
      acc = MFMA16(ql0, bh0, acc);
      acc = MFMA16(qh0, bl0, acc);
      acc = MFMA16(qh0, bh0, acc);
      acc = MFMA16(ql1, bh1, acc);
      acc = MFMA16(qh1, bl1, acc);
      acc = MFMA16(qh1, bh1, acc);
      const float rl = rlb[c * 32 + kr];
#pragma unroll
      for (int r = 0; r < 4; ++r) {
        float p = __expf(fminf(acc[r] * 0.125f, 60.f)) * rl;
        unsigned short h, l; split1(p, h, l);
        Ph[w][(lane >> 4) * 4 + r][kr] = h;
        Pl[w][(lane >> 4) * 4 + r][kr] = l;
      }
    }
    short8 pah = *(const short8*)&Ph[w][l15][dbase];
    short8 pal = *(const short8*)&Pl[w][l15][dbase];
#pragma unroll
    for (int ds = 0; ds < 4; ++ds) {
      const int dr = ds * 16 + l15;
      const int colb = (((dbase >> 3) ^ ((dr >> 3) & 3)) << 3);
      short8 vbh = *(const short8*)&Vth[par][dr][colb];
      short8 vbl = *(const short8*)&Vtl[par][dr][colb];
      accO[ds] = MFMA16(pal, vbh, accO[ds]);
      accO[ds] = MFMA16(pah, vbl, accO[ds]);
      accO[ds] = MFMA16(pah, vbh, accO[ds]);
    }
  }
  __syncthreads();
  if (par == 1) {
#pragma unroll
    for (int ds = 0; ds < 4; ++ds)
#pragma unroll
      for (int r = 0; r < 4; ++r)
        Comb[qsub][(lane >> 4) * 4 + r][ds * 16 + l15] = accO[ds][r];
  }
  __syncthreads();
  if (par == 0) {
    float* Ob = Out + ((size_t)(b * S_N + qBlk * 32 + qsub * 16)) * D_N;
#pragma unroll
    for (int ds = 0; ds < 4; ++ds)
#pragma unroll
      for (int r = 0; r < 4; ++r) {
        int qq = (lane >> 4) * 4 + r;
        int dd = ds * 16 + l15;
        Ob[((size_t)qq) * D_N + dd] = accO[ds][r] + Comb[qsub][qq][dd];
      }
  }
}

extern "C" void kernel_launch(void* const* d_in, const int* in_sizes, int n_in,
                              void* d_out, int out_size, void* d_ws, size_t ws_size,
                              hipStream_t stream) {
  (void)in_sizes; (void)n_in; (void)out_size;
  const float* Q = (const float*)d_in[0];
  const float* K = (const float*)d_in[1];
  const float* V = (const float*)d_in[2];
  float* out = (float*)d_out;
  uchar* ws = (uchar*)d_ws;

  const size_t imgSz = (size_t)B_N * NCHUNK * IMG_CH;          // 4 MB
  const size_t offK = 0;
  const size_t offQV = imgSz;                                  // Q image; VT aliases after stats
  const size_t offLP = 2 * imgSz;
  const size_t offRC = offLP + (size_t)8 * BS_N * 4;
  const size_t need3 = offRC + (size_t)BS_N * 4;               // ~8.9 MB
  const size_t needV1 = (size_t)3 * BS_N * 4;

  if (ws_size >= need3) {
    float* lPart = (float*)(ws + offLP);
    float* rcpl = (float*)(ws + offRC);
    sdpa_prep_split<<<dim3(512), dim3(256), 0, stream>>>(K, ws + offK, 1.0f);
    sdpa_prep_split<<<dim3(512), dim3(256), 0, stream>>>(Q, ws + offQV, QSC);
    sdpa_stats3<<<dim3(512), dim3(256), 0, stream>>>(ws + offK, ws + offQV, lPart);
    sdpa_finalize8<<<dim3(BS_N / 256), dim3(256), 0, stream>>>(lPart, rcpl);
    sdpa_prepV3<<<dim3(512), dim3(256), 0, stream>>>(V, rcpl, ws + offQV);
    sdpa_apply3<<<dim3(512), dim3(256), 0, stream>>>(Q, ws + offK, ws + offQV, out);
  } else if (ws_size >= needV1) {
    float* lPart = (float*)ws;
    float* rcpl = lPart + 2 * BS_N;
    sdpa_stats<<<dim3(512), dim3(256), 0, stream>>>(Q, K, lPart);
    sdpa_finalize<<<dim3(BS_N / 256), dim3(256), 0, stream>>>(lPart, rcpl);
    sdpa_apply_v1<<<dim3(512), dim3(256), 0, stream>>>(Q, K, V, rcpl, out);
  }
}

// Round 4
// 169.881 us; speedup vs baseline: 1.0188x; 1.0188x over previous
//
#include <hip/hip_runtime.h>

// B=4, S=4096, D=64, fp32. Softmax over QUERY axis (per key-column norm):
//   out[b,q,:] = sum_k exp(s[q,k]) * (1/sum_q' exp(s[q',k])) * V[k,:],  s = Q.K^T/8
// v4: software-pipelined register-direct design (fix: round-3 was latency-bound,
// MfmaUtil 16%, serial load->use chains).
//   prepKQ: K,Q -> hi/lo bf16 interleaved images (Q pre-scaled by 0.125*log2e)
//   stats4: column sums; K-frags register-resident; Q chunks double-buffered in regs
//   finalize8 -> rcpl; prepV3: VT image (rcpl folded), ALIASES Q image
//   apply4: K double-buffered in regs (prefetch it+1); PV decoupled one iteration
//           (P LDS round-trip crosses iter boundary); V loads issued at iter top.
// Numerics identical per-term to v3 (hi/lo split, 3-MFMA products).

#define B_N 4
#define S_N 4096
#define D_N 64
#define BS_N (B_N * S_N)
#define NCHUNK 128            // 32-row chunks per batch
#define IMG_CH 8192           // bytes per chunk in every image
#define QSC (0.125f * 1.44269504088896f)

typedef __attribute__((ext_vector_type(4))) float f32x4;
typedef __attribute__((ext_vector_type(8))) short short8;
typedef unsigned long long u64;
typedef unsigned char uchar;

#define MFMA16(A, Bf, C) __builtin_amdgcn_mfma_f32_16x16x32_bf16((A), (Bf), (C), 0, 0, 0)

// Truncation hi/lo split: x == hi + lo + O(2^-16 x); residual exact in fp32.
__device__ __forceinline__ void split1(float x, unsigned short& h, unsigned short& l) {
  union { float f; unsigned u; } t; t.f = x;
  h = (unsigned short)(t.u >> 16);
  union { unsigned u; float f; } hv; hv.u = ((unsigned)h) << 16;
  union { float f; unsigned u; } r; r.f = x - hv.f;
  l = (unsigned short)(r.u >> 16);
}

__device__ __forceinline__ void splitFrag8(const f32x4 a, const f32x4 b, short8& hi, short8& lo) {
#pragma unroll
  for (int j = 0; j < 4; ++j) { unsigned short h, l; split1(a[j], h, l); hi[j] = (short)h; lo[j] = (short)l; }
#pragma unroll
  for (int j = 0; j < 4; ++j) { unsigned short h, l; split1(b[j], h, l); hi[4 + j] = (short)h; lo[4 + j] = (short)l; }
}

// ---------------------------------------------------------------------------
// prepKQ: fp32 [B*S][64] -> chunk images: row r (32/chunk) = [hi 128B][lo 128B].
// grid 1024: blocks 0..511 = K (scale 1), 512..1023 = Q (scale QSC).
// ---------------------------------------------------------------------------
__global__ __launch_bounds__(256) void sdpa_prepKQ(const float* __restrict__ K,
                                                   const float* __restrict__ Qm,
                                                   uchar* __restrict__ Kimg,
                                                   uchar* __restrict__ Qimg) {
  const int sel = blockIdx.x >> 9;
  const int c = blockIdx.x & 127;
  const int b = (blockIdx.x >> 7) & 3;
  const float* src = sel ? Qm : K;
  uchar* img = sel ? Qimg : Kimg;
  const float scale = sel ? QSC : 1.0f;
  const int t = threadIdx.x;
  const int r = t >> 3;
  const int d0 = (t & 7) * 8;
  const float* s = src + ((size_t)(b * S_N + c * 32 + r)) * D_N + d0;
  f32x4 x0 = *(const f32x4*)(s);
  f32x4 x1 = *(const f32x4*)(s + 4);
  x0 *= scale; x1 *= scale;
  short8 h8, l8;
  splitFrag8(x0, x1, h8, l8);
  uchar* dst = img + ((size_t)(b * NCHUNK + c)) * IMG_CH + r * 256 + d0 * 2;
  *(short8*)(dst) = h8;
  *(short8*)(dst + 128) = l8;
}

// ---------------------------------------------------------------------------
// stats4: lPart[qs][b][k] = sum over q-slice qs (512 q) of exp2(min(s,86)).
// grid 512, block 256; wave w = q-slice. K (64 k) register-resident; Q chunks
// double-buffered in regs (prefetch it+1 while computing it). No barriers.
// ---------------------------------------------------------------------------
__global__ __launch_bounds__(256, 2) void sdpa_stats4(const uchar* __restrict__ Kimg,
                                                      const uchar* __restrict__ Qimg,
                                                      float* __restrict__ lPart) {
  const int tid = threadIdx.x, lane = tid & 63, w = tid >> 6;
  const int l15 = lane & 15, g4 = lane >> 4;
  const int xcd = blockIdx.x & 7;
  const int b = xcd >> 1;
  const int r = blockIdx.x >> 3;                  // [0,64)
  const int kt = ((r & 31) << 1) | (xcd & 1);     // [0,64) k-tile of 64
  const int qs = ((r >> 5) << 2) | w;             // [0,8) q-slice of 512

  // K resident: kg 0..3 -> rows kt*64+kg*16+l15 (chunk kt*2+(kg>>1))
  short8 kh[4][2], kl[4][2];
#pragma unroll
  for (int kg = 0; kg < 4; ++kg) {
    const uchar* kb = Kimg + ((size_t)(b * NCHUNK + kt * 2 + (kg >> 1))) * IMG_CH
                    + ((kg & 1) * 16 + l15) * 256 + (g4 << 4);
    kh[kg][0] = *(const short8*)(kb);
    kh[kg][1] = *(const short8*)(kb + 64);
    kl[kg][0] = *(const short8*)(kb + 128);
    kl[kg][1] = *(const short8*)(kb + 192);
  }

  float lacc[4][4];
#pragma unroll
  for (int kg = 0; kg < 4; ++kg)
#pragma unroll
    for (int rr = 0; rr < 4; ++rr) lacc[kg][rr] = 0.f;

  const uchar* Qbase = Qimg + ((size_t)(b * NCHUNK + qs * 16)) * IMG_CH + l15 * 256 + (g4 << 4);

  short8 qb[2][2][4];  // [buf][qt][bh0,bh1,bl0,bl1]
#pragma unroll
  for (int qt = 0; qt < 2; ++qt)
#pragma unroll
    for (int p = 0; p < 4; ++p)
      qb[0][qt][p] = *(const short8*)(Qbase + qt * 4096 + p * 64);

#pragma unroll 2
  for (int it = 0; it < 16; ++it) {
    const int cur = it & 1, nxt = cur ^ 1;
    if (it < 15) {
      const uchar* Qn = Qbase + (size_t)(it + 1) * IMG_CH;
#pragma unroll
      for (int qt = 0; qt < 2; ++qt)
#pragma unroll
        for (int p = 0; p < 4; ++p)
          qb[nxt][qt][p] = *(const short8*)(Qn + qt * 4096 + p * 64);
    }
#pragma unroll
    for (int qt = 0; qt < 2; ++qt) {
      short8 bh0 = qb[cur][qt][0], bh1 = qb[cur][qt][1];
      short8 bl0 = qb[cur][qt][2], bl1 = qb[cur][qt][3];
#pragma unroll
      for (int kg = 0; kg < 4; ++kg) {
        f32x4 acc = {0.f, 0.f, 0.f, 0.f};
        acc = MFMA16(kl[kg][0], bh0, acc);
        acc = MFMA16(kh[kg][0], bl0, acc);
        acc = MFMA16(kh[kg][0], bh0, acc);
        acc = MFMA16(kl[kg][1], bh1, acc);
        acc = MFMA16(kh[kg][1], bl1, acc);
        acc = MFMA16(kh[kg][1], bh1, acc);
#pragma unroll
        for (int rr = 0; rr < 4; ++rr)
          lacc[kg][rr] += exp2f(fminf(acc[rr], 86.f));
      }
    }
  }

#pragma unroll
  for (int off = 1; off < 16; off <<= 1)
#pragma unroll
    for (int kg = 0; kg < 4; ++kg)
#pragma unroll
      for (int rr = 0; rr < 4; ++rr)
        lacc[kg][rr] += __shfl_xor(lacc[kg][rr], off);

  if (l15 == 0) {
#pragma unroll
    for (int kg = 0; kg < 4; ++kg)
#pragma unroll
      for (int rr = 0; rr < 4; ++rr)
        lPart[(size_t)qs * BS_N + b * S_N + kt * 64 + kg * 16 + (g4 << 2) + rr] = lacc[kg][rr];
  }
}

__global__ void sdpa_finalize8(const float* __restrict__ lPart, float* __restrict__ rcpl) {
  int i = blockIdx.x * 256 + threadIdx.x;
  if (i < BS_N) {
    float s = 0.f;
#pragma unroll
    for (int j = 0; j < 8; ++j) s += lPart[(size_t)j * BS_N + i];
    rcpl[i] = 1.0f / s;
  }
}

// ---------------------------------------------------------------------------
// prepV3: VT chunk images: row d (64/chunk) = [hi 64B: 32 k][lo 64B], value
// bf16 split of V[k][d] * rcpl[k]. grid 512, block 256, LDS transpose.
// ---------------------------------------------------------------------------
__global__ __launch_bounds__(256) void sdpa_prepV3(const float* __restrict__ V,
                                                   const float* __restrict__ rcpl,
                                                   uchar* __restrict__ VT) {
  __shared__ float Vs[32][65];
  __shared__ float rls[32];
  const int c = blockIdx.x & 127;
  const int b = blockIdx.x >> 7;
  const int t = threadIdx.x;
  {
    const int k = t >> 3;
    const int d0 = (t & 7) * 8;
    const float* src = V + ((size_t)(b * S_N + c * 32 + k)) * D_N + d0;
    f32x4 x0 = *(const f32x4*)(src);
    f32x4 x1 = *(const f32x4*)(src + 4);
#pragma unroll
    for (int j = 0; j < 4; ++j) { Vs[k][d0 + j] = x0[j]; Vs[k][d0 + 4 + j] = x1[j]; }
    if (t < 32) rls[t] = rcpl[b * S_N + c * 32 + t];
  }
  __syncthreads();
  const int d = t >> 2;
  const int kg = t & 3;
  short8 h8, l8;
#pragma unroll
  for (int j = 0; j < 8; ++j) {
    int k = kg * 8 + j;
    float v = Vs[k][d] * rls[k];
    unsigned short h, l; split1(v, h, l);
    h8[j] = (short)h; l8[j] = (short)l;
  }
  uchar* dst = VT + ((size_t)(b * NCHUNK + c)) * IMG_CH + d * 128 + kg * 16;
  *(short8*)(dst) = h8;
  *(short8*)(dst + 64) = l8;
}

// ---------------------------------------------------------------------------
// apply4: grid 512 = b(4, XCD-paired) x qt(128 tiles of 32 q); block 256.
// Wave w = k-quarter (1024 k, 32 chunk-iters). Software-pipelined:
//   iter i: prefetch K(i+1) regs | load V(i-1) regs | QK(i)->P(i) LDS buf i&1
//           | PV(i-1) from buf (i-1)&1.  Epilogue: PV(31). One barrier (merge).
// ---------------------------------------------------------------------------
__global__ __launch_bounds__(256, 2) void sdpa_apply4(const float* __restrict__ Q,
                                                      const uchar* __restrict__ Kimg,
                                                      const uchar* __restrict__ VTimg,
                                                      float* __restrict__ Out) {
  // P: 4 waves x 2 bufs x (PH 2560 | PL 2560) = 40960; Comb merge reuses it.
  __shared__ __attribute__((aligned(16))) uchar sm[40960];

  const int tid = threadIdx.x, lane = tid & 63, w = tid >> 6;
  const int l15 = lane & 15, g4 = lane >> 4;
  const int xcd = blockIdx.x & 7;
  const int b = xcd >> 1;
  const int qt = ((blockIdx.x >> 3) << 1) | (xcd & 1);  // [0,128)

  // Q B-frags: raw fp32, scaled by QSC, hi/lo split (once per wave)
  short8 qh[2][2], ql[2][2];
#pragma unroll
  for (int qg = 0; qg < 2; ++qg) {
    const int qRow = qt * 32 + qg * 16 + l15;
    const float* Qp = Q + ((size_t)(b * S_N + qRow)) * D_N;
    f32x4 x0 = *(const f32x4*)(Qp + g4 * 8);
    f32x4 x1 = *(const f32x4*)(Qp + g4 * 8 + 4);
    f32x4 y0 = *(const f32x4*)(Qp + 32 + g4 * 8);
    f32x4 y1 = *(const f32x4*)(Qp + 36 + g4 * 8);
    x0 *= QSC; x1 *= QSC; y0 *= QSC; y1 *= QSC;
    splitFrag8(x0, x1, qh[qg][0], ql[qg][0]);
    splitFrag8(y0, y1, qh[qg][1], ql[qg][1]);
  }

  f32x4 accO[2][4];
#pragma unroll
  for (int qg = 0; qg < 2; ++qg)
#pragma unroll
    for (int dt = 0; dt < 4; ++dt) accO[qg][dt] = (f32x4){0.f, 0.f, 0.f, 0.f};

  const uchar* Kc = Kimg + ((size_t)(b * NCHUNK + w * 32)) * IMG_CH + l15 * 256 + (g4 << 4);
  const uchar* Vc = VTimg + ((size_t)(b * NCHUNK + w * 32)) * IMG_CH + l15 * 128 + (g4 << 4);

  uchar* const PH0 = sm + w * 5120;
  const int pwOff = l15 * 80 + (g4 << 3);  // b64 P write: + qg*1280 + kt*32
  const int prOff = l15 * 80 + (g4 << 4);  // b128 P read: + qg*1280

  // prologue: K chunk 0 resident
  short8 kb[2][2][4];  // [buf][kt][ah0,ah1,al0,al1]
#pragma unroll
  for (int kt = 0; kt < 2; ++kt)
#pragma unroll
    for (int p = 0; p < 4; ++p)
      kb[0][kt][p] = *(const short8*)(Kc + kt * 4096 + p * 64);

#pragma unroll 2
  for (int it = 0; it < 32; ++it) {
    const int cur = it & 1;
    const int nxt = cur ^ 1;

    // prefetch K(it+1)
    if (it < 31) {
      const uchar* Kn = Kc + (size_t)(it + 1) * IMG_CH;
#pragma unroll
      for (int kt = 0; kt < 2; ++kt)
#pragma unroll
        for (int p = 0; p < 4; ++p)
          kb[nxt][kt][p] = *(const short8*)(Kn + kt * 4096 + p * 64);
    }

    // V(it-1) for PV(it-1): issued here, consumed after QK+exp (~covered)
    short8 vv[4][2];
    if (it > 0) {
      const uchar* Vn = Vc + (size_t)(it - 1) * IMG_CH;
#pragma unroll
      for (int dt = 0; dt < 4; ++dt) {
        vv[dt][0] = *(const short8*)(Vn + dt * 2048);
        vv[dt][1] = *(const short8*)(Vn + dt * 2048 + 64);
      }
    }

    // QK(it) -> P(cur). Swapped (A=K, B=Q): D[k][q]; k = kt*16+g4*4+r, q = l15
    uchar* PH = PH0 + cur * 20480;
    uchar* PL = PH + 2560;
#pragma unroll
    for (int kt = 0; kt < 2; ++kt) {
      short8 ah0 = kb[cur][kt][0], ah1 = kb[cur][kt][1];
      short8 al0 = kb[cur][kt][2], al1 = kb[cur][kt][3];
#pragma unroll
      for (int qg = 0; qg < 2; ++qg) {
        f32x4 acc = {0.f, 0.f, 0.f, 0.f};
        acc = MFMA16(al0, qh[qg][0], acc);
        acc = MFMA16(ah0, ql[qg][0], acc);
        acc = MFMA16(ah0, qh[qg][0], acc);
        acc = MFMA16(al1, qh[qg][1], acc);
        acc = MFMA16(ah1, ql[qg][1], acc);
        acc = MFMA16(ah1, qh[qg][1], acc);
        u64 ph = 0ull, pl = 0ull;
#pragma unroll
        for (int r = 0; r < 4; ++r) {
          float p = exp2f(fminf(acc[r], 86.f));
          unsigned short h, l; split1(p, h, l);
          ph |= ((u64)h) << (16 * r);
          pl |= ((u64)l) << (16 * r);
        }
        *(u64*)(PH + qg * 1280 + kt * 32 + pwOff) = ph;
        *(u64*)(PL + qg * 1280 + kt * 32 + pwOff) = pl;
      }
    }

    // PV(it-1) from buf nxt == (it-1)&1
    if (it > 0) {
      const uchar* PHp = PH0 + nxt * 20480;
      const uchar* PLp = PHp + 2560;
      short8 pah[2], pal[2];
#pragma unroll
      for (int qg = 0; qg < 2; ++qg) {
        pah[qg] = *(const short8*)(PHp + qg * 1280 + prOff);
        pal[qg] = *(const short8*)(PLp + qg * 1280 + prOff);
      }
#pragma unroll
      for (int dt = 0; dt < 4; ++dt)
#pragma unroll
        for (int qg = 0; qg < 2; ++qg) {
          accO[qg][dt] = MFMA16(pal[qg], vv[dt][0], accO[qg][dt]);
          accO[qg][dt] = MFMA16(pah[qg], vv[dt][1], accO[qg][dt]);
          accO[qg][dt] = MFMA16(pah[qg], vv[dt][0], accO[qg][dt]);
        }
    }
  }

  // epilogue: PV(31) from buf 1
  {
    const uchar* Vn = Vc + (size_t)31 * IMG_CH;
    short8 vv[4][2];
#pragma unroll
    for (int dt = 0; dt < 4; ++dt) {
      vv[dt][0] = *(const short8*)(Vn + dt * 2048);
      vv[dt][1] = *(const short8*)(Vn + dt * 2048 + 64);
    }
    const uchar* PHp = PH0 + 20480;
    const uchar* PLp = PHp + 2560;
    short8 pah[2], pal[2];
#pragma unroll
    for (int qg = 0; qg < 2; ++qg) {
      pah[qg] = *(const short8*)(PHp + qg * 1280 + prOff);
      pal[qg] = *(const short8*)(PLp + qg * 1280 + prOff);
    }
#pragma unroll
    for (int dt = 0; dt < 4; ++dt)
#pragma unroll
      for (int qg = 0; qg < 2; ++qg) {
        accO[qg][dt] = MFMA16(pal[qg], vv[dt][0], accO[qg][dt]);
        accO[qg][dt] = MFMA16(pah[qg], vv[dt][1], accO[qg][dt]);
        accO[qg][dt] = MFMA16(pah[qg], vv[dt][0], accO[qg][dt]);
      }
  }

  // merge the 4 k-quarter partials (only barriers in the kernel)
  __syncthreads();
  float* CombW = (float*)sm + (size_t)w * 32 * 68;
#pragma unroll
  for (int qg = 0; qg < 2; ++qg)
#pragma unroll
    for (int dt = 0; dt < 4; ++dt)
#pragma unroll
      for (int r = 0; r < 4; ++r)
        CombW[(qg * 16 + (g4 << 2) + r) * 68 + dt * 16 + l15] = accO[qg][dt][r];
  __syncthreads();
  {
    const int row = tid >> 3;   // 0..31
    const int cb = tid & 7;     // 0..7
    const float* Cm = (const float*)sm;
    f32x4 s0 = {0.f, 0.f, 0.f, 0.f}, s1 = {0.f, 0.f, 0.f, 0.f};
#pragma unroll
    for (int w2 = 0; w2 < 4; ++w2) {
      const float* p = Cm + (size_t)w2 * 32 * 68 + row * 68 + cb * 8;
      s0 += *(const f32x4*)(p);
      s1 += *(const f32x4*)(p + 4);
    }
    float* Op = Out + ((size_t)(b * S_N + qt * 32 + row)) * D_N + cb * 8;
    *(f32x4*)(Op) = s0;
    *(f32x4*)(Op + 4) = s1;
  }
}

extern "C" void kernel_launch(void* const* d_in, const int* in_sizes, int n_in,
                              void* d_out, int out_size, void* d_ws, size_t ws_size,
                              hipStream_t stream) {
  (void)in_sizes; (void)n_in; (void)out_size;
  const float* Q = (const float*)d_in[0];
  const float* K = (const float*)d_in[1];
  const float* V = (const float*)d_in[2];
  float* out = (float*)d_out;
  uchar* ws = (uchar*)d_ws;

  const size_t imgSz = (size_t)B_N * NCHUNK * IMG_CH;          // 4 MB
  const size_t offK = 0;
  const size_t offQV = imgSz;                                  // Q image; VT aliases after stats
  const size_t offLP = 2 * imgSz;
  const size_t offRC = offLP + (size_t)8 * BS_N * 4;
  const size_t need = offRC + (size_t)BS_N * 4;                // ~8.9 MB (proven available)

  if (ws_size < need) return;
  float* lPart = (float*)(ws + offLP);
  float* rcpl = (float*)(ws + offRC);

  sdpa_prepKQ<<<dim3(1024), dim3(256), 0, stream>>>(K, Q, ws + offK, ws + offQV);
  sdpa_stats4<<<dim3(512), dim3(256), 0, stream>>>(ws + offK, ws + offQV, lPart);
  sdpa_finalize8<<<dim3(BS_N / 256), dim3(256), 0, stream>>>(lPart, rcpl);
  sdpa_prepV3<<<dim3(512), dim3(256), 0, stream>>>(V, rcpl, ws + offQV);
  sdpa_apply4<<<dim3(512), dim3(256), 0, stream>>>(Q, ws + offK, ws + offQV, out);
}